// Round 5
// baseline (504.877 us; speedup 1.0000x reference)
//
#include <hip/hip_runtime.h>
#include <hip/hip_bf16.h>
#include <cstdint>

#define USER_NUM 30000
#define ITEM_NUM 70000
#define NTOT     100000   // USER_NUM + ITEM_NUM

typedef __attribute__((ext_vector_type(8))) short bf16x8;
typedef __attribute__((ext_vector_type(8))) ushort u16x8;
typedef __attribute__((ext_vector_type(4))) float f32x4;

// fp32 -> (hi, lo) bf16 pair via truncation; a ~= hi + lo to ~2^-16 rel.
__device__ __forceinline__ void split2(float x, ushort& h, ushort& l) {
    unsigned u = __builtin_bit_cast(unsigned int, x);
    h = (ushort)(u >> 16);
    float hf = __builtin_bit_cast(float, u & 0xffff0000u);
    float lo = x - hf;
    l = (ushort)(__builtin_bit_cast(unsigned int, lo) >> 16);
}

// ---------------------------------------------------------------------------
// CSR build kernels
// ---------------------------------------------------------------------------

__global__ void hist_rows(const int* __restrict__ erow, int* __restrict__ counts, int nnz) {
    int i = blockIdx.x * blockDim.x + threadIdx.x;
    if (i < nnz) atomicAdd(&counts[erow[i]], 1);
}

__global__ void scan_block(const int* __restrict__ counts, int* __restrict__ row_ptr,
                           int* __restrict__ blk_sums, int n) {
    __shared__ int sd[1024];
    int i = blockIdx.x * 1024 + threadIdx.x;
    int v = (i < n) ? counts[i] : 0;
    sd[threadIdx.x] = v;
    __syncthreads();
    for (int off = 1; off < 1024; off <<= 1) {
        int t = (threadIdx.x >= off) ? sd[threadIdx.x - off] : 0;
        __syncthreads();
        sd[threadIdx.x] += t;
        __syncthreads();
    }
    if (i < n) row_ptr[i] = sd[threadIdx.x] - v;   // block-local exclusive
    if (threadIdx.x == 1023) blk_sums[blockIdx.x] = sd[1023];
}

__global__ void scan_sums(int* __restrict__ blk_sums, int nb) {
    __shared__ int sd[128];
    int v = (threadIdx.x < nb) ? blk_sums[threadIdx.x] : 0;
    sd[threadIdx.x] = v;
    __syncthreads();
    for (int off = 1; off < 128; off <<= 1) {
        int t = (threadIdx.x >= off) ? sd[threadIdx.x - off] : 0;
        __syncthreads();
        sd[threadIdx.x] += t;
        __syncthreads();
    }
    if (threadIdx.x < nb) blk_sums[threadIdx.x] = sd[threadIdx.x] - v;  // exclusive
}

__global__ void scan_add(int* __restrict__ row_ptr, const int* __restrict__ blk_sums,
                         int n, int nnz) {
    int i = blockIdx.x * 1024 + threadIdx.x;
    if (i < n) row_ptr[i] += blk_sums[blockIdx.x];
    if (blockIdx.x == 0 && threadIdx.x == 0) row_ptr[n] = nnz;
}

__global__ void scatter_edges(const int* __restrict__ erow, const int* __restrict__ ecol,
                              const float* __restrict__ eval,
                              const int* __restrict__ row_ptr, int* __restrict__ fill,
                              int* __restrict__ scol, float* __restrict__ sval, int nnz) {
    int i = blockIdx.x * blockDim.x + threadIdx.x;
    if (i >= nnz) return;
    int r = erow[i];
    int pos = row_ptr[r] + atomicAdd(&fill[r], 1);
    scol[pos] = ecol[i];
    sval[pos] = eval[i];
}

// ---------------------------------------------------------------------------
// Pre-split a weight matrix into hi/lo bf16 arrays (done once per launch).
// ---------------------------------------------------------------------------

__global__ void split_w(const float* __restrict__ W, ushort* __restrict__ Wh,
                        ushort* __restrict__ Wl, int n) {
    int i = blockIdx.x * blockDim.x + threadIdx.x;
    if (i >= n) return;
    ushort h, l;
    split2(W[i], h, l);
    Wh[i] = h;
    Wl[i] = l;
}

// ---------------------------------------------------------------------------
// Dual split-bf16 MFMA GEMM, register-pipelined K-loop:
//   C1 = A @ W1^T + b1 + b2 ;  C2 = (A @ W1^T) + (A*A) @ W2^T   (no bias)
// A = virtual row-concat [xa ; xb] split at `split`, rows length KK (ct, even/BK).
// TM=128, block 256 = 4 waves (2x2), wave tile 64 x (TN/2), BK=32.
// Next iteration's A-raw (global fp32) and B-fragments (pre-split bf16 global,
// L1/L2-hit) are prefetched into a second register slot during the MFMA phase,
// so global latency hides under MFMA. 2-deep unrolled to avoid reg copies.
// ---------------------------------------------------------------------------

template <int TN, int KK>
__global__ __launch_bounds__(256, 2)
void gemm_dual_mfma(const float* __restrict__ xa, const float* __restrict__ xb, int split,
                    const ushort* __restrict__ W1h, const ushort* __restrict__ W1l,
                    const ushort* __restrict__ W2h, const ushort* __restrict__ W2l,
                    const float* __restrict__ bias1, const float* __restrict__ bias2,
                    float* __restrict__ C1, float* __restrict__ C2,
                    int M, int Nout) {
    constexpr int TM = 128, BK = 32, SR = BK + 8;
    constexpr int NITER = KK / BK;            // even by construction
    constexpr int WTM = 64, WTN = TN / 2;
    constexpr int MI = WTM / 16, NI = WTN / 16;
    __shared__ ushort Ah[TM * SR], Al[TM * SR], Sh[TM * SR], Sl[TM * SR];

    const int m0 = blockIdx.y * TM;
    const int n0 = blockIdx.x * TN;
    const int t  = threadIdx.x;
    const int lane = t & 63, w = t >> 6;
    const int wm = w & 1, wn = w >> 1;
    const int lm = lane & 15, lq = lane >> 4;

    const int srow = t >> 1, shalf = t & 1;
    const int sgm = m0 + srow;
    const bool svalid = (sgm < M);
    const float* srcrow = svalid ? ((sgm < split) ? xa + (size_t)sgm * KK
                                                  : xb + (size_t)(sgm - split) * KK)
                                 : xa;
    const int sbase = srow * SR + shalf * 16;

    float4 AR[2][4] = {};
    bf16x8 Bh1[2][NI], Bl1[2][NI], Bh2[2][NI], Bl2[2][NI];
    f32x4 acc1[MI][NI] = {};
    f32x4 acc2[MI][NI] = {};

    auto loadA = [&](float4 (&ar)[4], int it) {
        if (!svalid) return;
        const float* p = srcrow + it * BK + shalf * 16;
#pragma unroll
        for (int q = 0; q < 4; ++q) ar[q] = *(const float4*)(p + q * 4);
    };
    auto stageA = [&](const float4 (&ar)[4]) {
        ushort hb[16], lb[16], shb[16], slb[16];
#pragma unroll
        for (int q = 0; q < 4; ++q) {
            const float av[4] = {ar[q].x, ar[q].y, ar[q].z, ar[q].w};
#pragma unroll
            for (int j = 0; j < 4; ++j) {
                int e = q * 4 + j;
                split2(av[j], hb[e], lb[e]);
                float sq = av[j] * av[j];
                split2(sq, shb[e], slb[e]);
            }
        }
        *(u16x8*)(Ah + sbase)     = *(const u16x8*)&hb[0];
        *(u16x8*)(Ah + sbase + 8) = *(const u16x8*)&hb[8];
        *(u16x8*)(Al + sbase)     = *(const u16x8*)&lb[0];
        *(u16x8*)(Al + sbase + 8) = *(const u16x8*)&lb[8];
        *(u16x8*)(Sh + sbase)     = *(const u16x8*)&shb[0];
        *(u16x8*)(Sh + sbase + 8) = *(const u16x8*)&shb[8];
        *(u16x8*)(Sl + sbase)     = *(const u16x8*)&slb[0];
        *(u16x8*)(Sl + sbase + 8) = *(const u16x8*)&slb[8];
    };
    auto loadB = [&](bf16x8 (&h1)[NI], bf16x8 (&l1)[NI],
                     bf16x8 (&h2)[NI], bf16x8 (&l2)[NI], int it) {
#pragma unroll
        for (int ni = 0; ni < NI; ++ni) {
            size_t wo = (size_t)(n0 + wn * WTN + ni * 16 + lm) * KK + it * BK + lq * 8;
            h1[ni] = *(const bf16x8*)(W1h + wo);
            l1[ni] = *(const bf16x8*)(W1l + wo);
            h2[ni] = *(const bf16x8*)(W2h + wo);
            l2[ni] = *(const bf16x8*)(W2l + wo);
        }
    };
    auto mfmaPhase = [&](bf16x8 (&h1)[NI], bf16x8 (&l1)[NI],
                         bf16x8 (&h2)[NI], bf16x8 (&l2)[NI]) {
#pragma unroll
        for (int mi = 0; mi < MI; ++mi) {
            int off = (wm * WTM + mi * 16 + lm) * SR + lq * 8;
            bf16x8 ah = *(const bf16x8*)(Ah + off);
            bf16x8 al = *(const bf16x8*)(Al + off);
            bf16x8 qh = *(const bf16x8*)(Sh + off);
            bf16x8 ql = *(const bf16x8*)(Sl + off);
#pragma unroll
            for (int ni = 0; ni < NI; ++ni) {
                acc1[mi][ni] = __builtin_amdgcn_mfma_f32_16x16x32_bf16(ah, h1[ni], acc1[mi][ni], 0, 0, 0);
                acc1[mi][ni] = __builtin_amdgcn_mfma_f32_16x16x32_bf16(ah, l1[ni], acc1[mi][ni], 0, 0, 0);
                acc1[mi][ni] = __builtin_amdgcn_mfma_f32_16x16x32_bf16(al, h1[ni], acc1[mi][ni], 0, 0, 0);
                acc2[mi][ni] = __builtin_amdgcn_mfma_f32_16x16x32_bf16(qh, h2[ni], acc2[mi][ni], 0, 0, 0);
                acc2[mi][ni] = __builtin_amdgcn_mfma_f32_16x16x32_bf16(qh, l2[ni], acc2[mi][ni], 0, 0, 0);
                acc2[mi][ni] = __builtin_amdgcn_mfma_f32_16x16x32_bf16(ql, h2[ni], acc2[mi][ni], 0, 0, 0);
            }
        }
    };

    // prologue
    loadA(AR[0], 0);
    loadB(Bh1[0], Bl1[0], Bh2[0], Bl2[0], 0);
    stageA(AR[0]);
    __syncthreads();

    for (int it = 0; it < NITER; it += 2) {
        if (it + 1 < NITER) {
            loadA(AR[1], it + 1);
            loadB(Bh1[1], Bl1[1], Bh2[1], Bl2[1], it + 1);
        }
        mfmaPhase(Bh1[0], Bl1[0], Bh2[0], Bl2[0]);
        __syncthreads();
        if (it + 1 < NITER) {
            stageA(AR[1]);
            __syncthreads();
            if (it + 2 < NITER) {
                loadA(AR[0], it + 2);
                loadB(Bh1[0], Bl1[0], Bh2[0], Bl2[0], it + 2);
            }
            mfmaPhase(Bh1[1], Bl1[1], Bh2[1], Bl2[1]);
            __syncthreads();
            if (it + 2 < NITER) {
                stageA(AR[0]);
                __syncthreads();
            }
        }
    }

    // ---- epilogue: C/D layout col=lane&15, row=lq*4+r; biases folded into C1 ----
#pragma unroll
    for (int mi = 0; mi < MI; ++mi)
#pragma unroll
        for (int ni = 0; ni < NI; ++ni)
#pragma unroll
            for (int r = 0; r < 4; ++r) {
                int gm = m0 + wm * WTM + mi * 16 + lq * 4 + r;
                int gn = n0 + wn * WTN + ni * 16 + lm;
                if (gm < M && gn < Nout) {
                    size_t o = (size_t)gm * Nout + gn;
                    float g1 = acc1[mi][ni][r];
                    C1[o] = g1 + bias1[gn] + bias2[gn];
                    C2[o] = g1 + acc2[mi][ni][r];
                }
            }
}

// ---------------------------------------------------------------------------
// T1 GEMM with fused gather, register-pipelined:
//   e1 = relu( [final[u] ; final[it+U]] @ T1_W^T + T1_b ),  K = 896
// final = [embd(256) | f1(128) | f2(64)] per node; A-rows gathered on the fly
// (all segment boundaries are 16-aligned so each staging thread's 16-float
// chunk lies in exactly one segment).
// ---------------------------------------------------------------------------

template <int TN, int KK>
__global__ __launch_bounds__(256, 2)
void gemm_t1_mfma(const int* __restrict__ userIdx, const int* __restrict__ itemIdx,
                  const float* __restrict__ uEmbd, const float* __restrict__ iEmbd,
                  const float* __restrict__ f1, const float* __restrict__ f2,
                  const ushort* __restrict__ Wh, const ushort* __restrict__ Wl,
                  const float* __restrict__ bias, float* __restrict__ C,
                  int M, int Nout) {
    constexpr int TM = 128, BK = 32, SR = BK + 8;
    constexpr int NITER = KK / BK;            // 28, even
    constexpr int WTM = 64, WTN = TN / 2;
    constexpr int MI = WTM / 16, NI = WTN / 16;
    __shared__ ushort Ah[TM * SR], Al[TM * SR];

    const int m0 = blockIdx.y * TM;
    const int n0 = blockIdx.x * TN;
    const int t  = threadIdx.x;
    const int lane = t & 63, w = t >> 6;
    const int wm = w & 1, wn = w >> 1;
    const int lm = lane & 15, lq = lane >> 4;

    const int srow = t >> 1, shalf = t & 1;
    const int b = m0 + srow;
    const bool svalid = (b < M);
    int unode = 0, gnode = 0;
    if (svalid) { unode = userIdx[b]; gnode = itemIdx[b] + USER_NUM; }
    const int sbase = srow * SR + shalf * 16;

    float4 AR[2][4] = {};
    bf16x8 Bh[2][NI], Bl[2][NI];
    f32x4 acc[MI][NI] = {};

    auto loadA = [&](float4 (&ar)[4], int it) {
        if (!svalid) return;
        int c0 = it * BK + shalf * 16;
        int node = (c0 < 448) ? unode : gnode;
        int cc = (c0 < 448) ? c0 : c0 - 448;
        const float* p;
        if (cc < 256)
            p = (node < USER_NUM) ? uEmbd + (size_t)node * 256 + cc
                                  : iEmbd + (size_t)(node - USER_NUM) * 256 + cc;
        else if (cc < 384) p = f1 + (size_t)node * 128 + (cc - 256);
        else               p = f2 + (size_t)node * 64  + (cc - 384);
#pragma unroll
        for (int q = 0; q < 4; ++q) ar[q] = *(const float4*)(p + q * 4);
    };
    auto stageA = [&](const float4 (&ar)[4]) {
        ushort hb[16], lb[16];
#pragma unroll
        for (int q = 0; q < 4; ++q) {
            const float av[4] = {ar[q].x, ar[q].y, ar[q].z, ar[q].w};
#pragma unroll
            for (int j = 0; j < 4; ++j) split2(av[j], hb[q * 4 + j], lb[q * 4 + j]);
        }
        *(u16x8*)(Ah + sbase)     = *(const u16x8*)&hb[0];
        *(u16x8*)(Ah + sbase + 8) = *(const u16x8*)&hb[8];
        *(u16x8*)(Al + sbase)     = *(const u16x8*)&lb[0];
        *(u16x8*)(Al + sbase + 8) = *(const u16x8*)&lb[8];
    };
    auto loadB = [&](bf16x8 (&h)[NI], bf16x8 (&l)[NI], int it) {
#pragma unroll
        for (int ni = 0; ni < NI; ++ni) {
            size_t wo = (size_t)(n0 + wn * WTN + ni * 16 + lm) * KK + it * BK + lq * 8;
            h[ni] = *(const bf16x8*)(Wh + wo);
            l[ni] = *(const bf16x8*)(Wl + wo);
        }
    };
    auto mfmaPhase = [&](bf16x8 (&h)[NI], bf16x8 (&l)[NI]) {
#pragma unroll
        for (int mi = 0; mi < MI; ++mi) {
            int off = (wm * WTM + mi * 16 + lm) * SR + lq * 8;
            bf16x8 ah = *(const bf16x8*)(Ah + off);
            bf16x8 al = *(const bf16x8*)(Al + off);
#pragma unroll
            for (int ni = 0; ni < NI; ++ni) {
                acc[mi][ni] = __builtin_amdgcn_mfma_f32_16x16x32_bf16(ah, h[ni], acc[mi][ni], 0, 0, 0);
                acc[mi][ni] = __builtin_amdgcn_mfma_f32_16x16x32_bf16(ah, l[ni], acc[mi][ni], 0, 0, 0);
                acc[mi][ni] = __builtin_amdgcn_mfma_f32_16x16x32_bf16(al, h[ni], acc[mi][ni], 0, 0, 0);
            }
        }
    };

    loadA(AR[0], 0);
    loadB(Bh[0], Bl[0], 0);
    stageA(AR[0]);
    __syncthreads();

    for (int it = 0; it < NITER; it += 2) {
        if (it + 1 < NITER) {
            loadA(AR[1], it + 1);
            loadB(Bh[1], Bl[1], it + 1);
        }
        mfmaPhase(Bh[0], Bl[0]);
        __syncthreads();
        if (it + 1 < NITER) {
            stageA(AR[1]);
            __syncthreads();
            if (it + 2 < NITER) {
                loadA(AR[0], it + 2);
                loadB(Bh[0], Bl[0], it + 2);
            }
            mfmaPhase(Bh[1], Bl[1]);
            __syncthreads();
            if (it + 2 < NITER) {
                stageA(AR[0]);
                __syncthreads();
            }
        }
    }

#pragma unroll
    for (int mi = 0; mi < MI; ++mi)
#pragma unroll
        for (int ni = 0; ni < NI; ++ni)
#pragma unroll
            for (int r = 0; r < 4; ++r) {
                int gm = m0 + wm * WTM + mi * 16 + lq * 4 + r;
                int gn = n0 + wn * WTN + ni * 16 + lm;
                if (gm < M && gn < Nout)
                    C[(size_t)gm * Nout + gn] = fmaxf(acc[mi][ni][r] + bias[gn], 0.f);
            }
}

// ---------------------------------------------------------------------------
// Fused SPMM epilogue (biases pre-folded into G1):
//   out[r,:] = sum_e val_e * H[col_e,:] + G1[r,:]
// 4 rows per 256-thread block, one wave per row, VEC floats per lane.
// ---------------------------------------------------------------------------

template <int VEC>
__global__ __launch_bounds__(256)
void spmm_fused(const int* __restrict__ row_ptr, const int* __restrict__ scol,
                const float* __restrict__ sval, const float* __restrict__ H,
                const float* __restrict__ G1, float* __restrict__ out, int n) {
    constexpr int W = 64 * VEC;
    int r = blockIdx.x * 4 + (threadIdx.x >> 6);
    if (r >= n) return;
    int base = (threadIdx.x & 63) * VEC;
    float acc[VEC];
    const float* g = G1 + (size_t)r * W + base;
#pragma unroll
    for (int v = 0; v < VEC; ++v) acc[v] = g[v];
    int e0 = row_ptr[r], e1 = row_ptr[r + 1];
    for (int e = e0; e < e1; ++e) {
        int c = scol[e];
        float val = sval[e];
        const float* h = H + (size_t)c * W + base;
#pragma unroll
        for (int v = 0; v < VEC; ++v) acc[v] += val * h[v];
    }
    float* o = out + (size_t)r * W + base;
#pragma unroll
    for (int v = 0; v < VEC; ++v) o[v] = acc[v];
}

// ---------------------------------------------------------------------------
// Fused T2+T3 tail: out[b] = T3_W . relu(T2_W @ e1[b] + T2_b) + T3_b
// One wave per batch row; lanes 0..31 each own one of the 32 T2 outputs.
// ---------------------------------------------------------------------------

__global__ __launch_bounds__(256)
void mlp_tail(const float* __restrict__ e1, const float* __restrict__ T2_W,
              const float* __restrict__ T2_b, const float* __restrict__ T3_W,
              const float* __restrict__ T3_b, float* __restrict__ out, int B) {
    int wid = (blockIdx.x * 256 + threadIdx.x) >> 6;
    if (wid >= B) return;
    int lane = threadIdx.x & 63;
    float s = 0.f;
    if (lane < 32) {
        const float* er = e1 + (size_t)wid * 64;
        const float* wr = T2_W + lane * 64;
        float d = T2_b[lane];
#pragma unroll
        for (int k = 0; k < 64; ++k) d += er[k] * wr[k];
        s = fmaxf(d, 0.f) * T3_W[lane];
    }
#pragma unroll
    for (int off2 = 16; off2 > 0; off2 >>= 1) s += __shfl_down(s, off2);
    if (lane == 0) out[wid] = s + T3_b[0];
}

// ---------------------------------------------------------------------------

extern "C" void kernel_launch(void* const* d_in, const int* in_sizes, int n_in,
                              void* d_out, int out_size, void* d_ws, size_t ws_size,
                              hipStream_t stream) {
    const int* userIdx  = (const int*)d_in[0];
    const int* itemIdx  = (const int*)d_in[1];
    const int* edge_row = (const int*)d_in[2];
    const int* edge_col = (const int*)d_in[3];
    const float* edge_val = (const float*)d_in[4];
    const float* uEmbd  = (const float*)d_in[5];
    const float* iEmbd  = (const float*)d_in[6];
    const float* W1_0 = (const float*)d_in[7];
    const float* b1_0 = (const float*)d_in[8];
    const float* W2_0 = (const float*)d_in[9];
    const float* b2_0 = (const float*)d_in[10];
    const float* W1_1 = (const float*)d_in[11];
    const float* b1_1 = (const float*)d_in[12];
    const float* W2_1 = (const float*)d_in[13];
    const float* b2_1 = (const float*)d_in[14];
    const float* T1_W = (const float*)d_in[15];
    const float* T1_b = (const float*)d_in[16];
    const float* T2_W = (const float*)d_in[17];
    const float* T2_b = (const float*)d_in[18];
    const float* T3_W = (const float*)d_in[19];
    const float* T3_b = (const float*)d_in[20];
    float* out = (float*)d_out;

    const int B   = in_sizes[0];
    const int NNZ = in_sizes[2];
    const int N   = NTOT;

    // ---- workspace carve-up (bytes, 256-aligned) ----
    uint8_t* ws = (uint8_t*)d_ws;
    size_t off = 0;
    auto alloc = [&](size_t bytes) {
        void* p = ws + off;
        off += (bytes + 255) & ~(size_t)255;
        return p;
    };
    float* bufA = (float*)alloc((size_t)N * 128 * 4);  // G1_0; later G1_1 | H_1
    float* bufB = (float*)alloc((size_t)N * 128 * 4);  // H_0;  later f2
    float* f1   = (float*)alloc((size_t)N * 128 * 4);
    float* e1   = (float*)alloc((size_t)B * 64 * 4);
    int*   counts  = (int*)alloc((size_t)2 * N * 4);   // counts[N] + fill[N]
    int*   fill    = counts + N;
    int*   row_ptr = (int*)alloc((size_t)(N + 1) * 4);
    int*   blk_sums= (int*)alloc(128 * 4);
    int*   scol    = (int*)alloc((size_t)NNZ * 4);
    float* sval    = (float*)alloc((size_t)NNZ * 4);
    // pre-split weight matrices (hi/lo bf16 stored as ushort)
    ushort* W10h = (ushort*)alloc(128 * 256 * 2);
    ushort* W10l = (ushort*)alloc(128 * 256 * 2);
    ushort* W20h = (ushort*)alloc(128 * 256 * 2);
    ushort* W20l = (ushort*)alloc(128 * 256 * 2);
    ushort* W11h = (ushort*)alloc(64 * 128 * 2);
    ushort* W11l = (ushort*)alloc(64 * 128 * 2);
    ushort* W21h = (ushort*)alloc(64 * 128 * 2);
    ushort* W21l = (ushort*)alloc(64 * 128 * 2);
    ushort* T1h  = (ushort*)alloc(64 * 896 * 2);
    ushort* T1l  = (ushort*)alloc(64 * 896 * 2);
    (void)ws_size; (void)n_in; (void)out_size;

    float* G1_0 = bufA;
    float* H_0  = bufB;
    float* G1_1 = bufA;
    float* H_1  = bufA + (size_t)N * 64;
    float* f2   = bufB;

    // ---- build CSR ----
    hipMemsetAsync(counts, 0, (size_t)2 * N * 4, stream);
    hist_rows<<<(NNZ + 255) / 256, 256, 0, stream>>>(edge_row, counts, NNZ);
    int nb = (N + 1023) / 1024;   // 98
    scan_block<<<nb, 1024, 0, stream>>>(counts, row_ptr, blk_sums, N);
    scan_sums<<<1, 128, 0, stream>>>(blk_sums, nb);
    scan_add<<<nb, 1024, 0, stream>>>(row_ptr, blk_sums, N, NNZ);
    scatter_edges<<<(NNZ + 255) / 256, 256, 0, stream>>>(edge_row, edge_col, edge_val,
                                                         row_ptr, fill, scol, sval, NNZ);

    // ---- pre-split weights ----
    split_w<<<(32768 + 255) / 256, 256, 0, stream>>>(W1_0, W10h, W10l, 32768);
    split_w<<<(32768 + 255) / 256, 256, 0, stream>>>(W2_0, W20h, W20l, 32768);
    split_w<<<(8192 + 255) / 256, 256, 0, stream>>>(W1_1, W11h, W11l, 8192);
    split_w<<<(8192 + 255) / 256, 256, 0, stream>>>(W2_1, W21h, W21l, 8192);
    split_w<<<(57344 + 255) / 256, 256, 0, stream>>>(T1_W, T1h, T1l, 57344);

    // ---- layer 0: G1_0 = F@W1_0^T (+biases), H_0 = F@W1_0^T + (F*F)@W2_0^T ----
    {
        dim3 grid(2, (N + 127) / 128);   // TN=64, Nout=128
        gemm_dual_mfma<64, 256><<<grid, 256, 0, stream>>>(
            uEmbd, iEmbd, USER_NUM, W10h, W10l, W20h, W20l, b1_0, b2_0, G1_0, H_0, N, 128);
    }
    // f1 = spmm(H_0) + G1_0   (biases already in G1_0)
    spmm_fused<2><<<(N + 3) / 4, 256, 0, stream>>>(row_ptr, scol, sval, H_0, G1_0, f1, N);

    // ---- layer 1: G1_1 = f1@W1_1^T (+biases), H_1 = f1@W1_1^T + (f1*f1)@W2_1^T ----
    {
        dim3 grid(1, (N + 127) / 128);   // TN=64, Nout=64
        gemm_dual_mfma<64, 128><<<grid, 256, 0, stream>>>(
            f1, f1, N, W11h, W11l, W21h, W21l, b1_1, b2_1, G1_1, H_1, N, 64);
    }
    // f2 = spmm(H_1) + G1_1
    spmm_fused<1><<<(N + 3) / 4, 256, 0, stream>>>(row_ptr, scol, sval, H_1, G1_1, f2, N);

    // ---- fused gather + T1 GEMM, then fused T2+T3 tail ----
    {
        dim3 grid(1, (B + 127) / 128);   // TN=64, K=896
        gemm_t1_mfma<64, 896><<<grid, 256, 0, stream>>>(
            userIdx, itemIdx, uEmbd, iEmbd, f1, f2, T1h, T1l, T1_b, e1, B, 64);
    }
    mlp_tail<<<(B * 64 + 255) / 256, 256, 0, stream>>>(e1, T2_W, T2_b, T3_W, T3_b, out, B);
}

// Round 6
// 483.416 us; speedup vs baseline: 1.0444x; 1.0444x over previous
//
#include <hip/hip_runtime.h>
#include <hip/hip_bf16.h>
#include <cstdint>

#define USER_NUM 30000
#define ITEM_NUM 70000
#define NTOT     100000   // USER_NUM + ITEM_NUM

typedef __attribute__((ext_vector_type(8))) short bf16x8;
typedef __attribute__((ext_vector_type(8))) ushort u16x8;
typedef __attribute__((ext_vector_type(4))) float f32x4;

// fp32 -> (hi, lo) bf16 pair via truncation; a ~= hi + lo to ~2^-16 rel.
__device__ __forceinline__ void split2(float x, ushort& h, ushort& l) {
    unsigned u = __builtin_bit_cast(unsigned int, x);
    h = (ushort)(u >> 16);
    float hf = __builtin_bit_cast(float, u & 0xffff0000u);
    float lo = x - hf;
    l = (ushort)(__builtin_bit_cast(unsigned int, lo) >> 16);
}

// ---------------------------------------------------------------------------
// CSR build kernels
// ---------------------------------------------------------------------------

__global__ void hist_rows(const int* __restrict__ erow, int* __restrict__ counts, int nnz) {
    int i = blockIdx.x * blockDim.x + threadIdx.x;
    if (i < nnz) atomicAdd(&counts[erow[i]], 1);
}

__global__ void scan_block(const int* __restrict__ counts, int* __restrict__ row_ptr,
                           int* __restrict__ blk_sums, int n) {
    __shared__ int sd[1024];
    int i = blockIdx.x * 1024 + threadIdx.x;
    int v = (i < n) ? counts[i] : 0;
    sd[threadIdx.x] = v;
    __syncthreads();
    for (int off = 1; off < 1024; off <<= 1) {
        int t = (threadIdx.x >= off) ? sd[threadIdx.x - off] : 0;
        __syncthreads();
        sd[threadIdx.x] += t;
        __syncthreads();
    }
    if (i < n) row_ptr[i] = sd[threadIdx.x] - v;   // block-local exclusive
    if (threadIdx.x == 1023) blk_sums[blockIdx.x] = sd[1023];
}

__global__ void scan_sums(int* __restrict__ blk_sums, int nb) {
    __shared__ int sd[128];
    int v = (threadIdx.x < nb) ? blk_sums[threadIdx.x] : 0;
    sd[threadIdx.x] = v;
    __syncthreads();
    for (int off = 1; off < 128; off <<= 1) {
        int t = (threadIdx.x >= off) ? sd[threadIdx.x - off] : 0;
        __syncthreads();
        sd[threadIdx.x] += t;
        __syncthreads();
    }
    if (threadIdx.x < nb) blk_sums[threadIdx.x] = sd[threadIdx.x] - v;  // exclusive
}

__global__ void scan_add(int* __restrict__ row_ptr, const int* __restrict__ blk_sums,
                         int n, int nnz) {
    int i = blockIdx.x * 1024 + threadIdx.x;
    if (i < n) row_ptr[i] += blk_sums[blockIdx.x];
    if (blockIdx.x == 0 && threadIdx.x == 0) row_ptr[n] = nnz;
}

__global__ void scatter_edges(const int* __restrict__ erow, const int* __restrict__ ecol,
                              const float* __restrict__ eval,
                              const int* __restrict__ row_ptr, int* __restrict__ fill,
                              int* __restrict__ scol, float* __restrict__ sval, int nnz) {
    int i = blockIdx.x * blockDim.x + threadIdx.x;
    if (i >= nnz) return;
    int r = erow[i];
    int pos = row_ptr[r] + atomicAdd(&fill[r], 1);
    scol[pos] = ecol[i];
    sval[pos] = eval[i];
}

// ---------------------------------------------------------------------------
// Pre-split a weight matrix into hi/lo bf16 arrays (done once per launch).
// ---------------------------------------------------------------------------

__global__ void split_w(const float* __restrict__ W, ushort* __restrict__ Wh,
                        ushort* __restrict__ Wl, int n) {
    int i = blockIdx.x * blockDim.x + threadIdx.x;
    if (i >= n) return;
    ushort h, l;
    split2(W[i], h, l);
    Wh[i] = h;
    Wl[i] = l;
}

// ---------------------------------------------------------------------------
// Dual split-bf16 MFMA GEMM (R4 simple 2-barrier loop, 4 blocks/CU):
//   C1 = A @ W1^T + b1 + b2 ;  C2 = (A @ W1^T) + (A*A) @ W2^T
// A = virtual row-concat [xa ; xb] split at `split`, rows length KK (ct).
// TM=128, block 256 = 4 waves (2x2): wave tile 64 x (TN/2). BK=32.
// LDS 40 KB (A hi/lo + square hi/lo) -> exactly 4 blocks/CU; VGPR ~64 ->
// occupancy-limited by LDS at 16 waves/CU. W fragments read straight from
// global (pre-split bf16, same addrs across blocks -> L1/L2-hit b128 loads).
// ---------------------------------------------------------------------------

template <int TN, int KK>
__global__ __launch_bounds__(256, 4)
void gemm_dual_mfma(const float* __restrict__ xa, const float* __restrict__ xb, int split,
                    const ushort* __restrict__ W1h, const ushort* __restrict__ W1l,
                    const ushort* __restrict__ W2h, const ushort* __restrict__ W2l,
                    const float* __restrict__ bias1, const float* __restrict__ bias2,
                    float* __restrict__ C1, float* __restrict__ C2,
                    int M, int Nout) {
    constexpr int TM = 128, BK = 32, SR = BK + 8;
    constexpr int NITER = KK / BK;
    constexpr int WTM = 64, WTN = TN / 2;
    constexpr int MI = WTM / 16, NI = WTN / 16;
    __shared__ ushort Ah[TM * SR], Al[TM * SR], Sh[TM * SR], Sl[TM * SR];

    const int m0 = blockIdx.y * TM;
    const int n0 = blockIdx.x * TN;
    const int t  = threadIdx.x;
    const int lane = t & 63, w = t >> 6;
    const int wm = w & 1, wn = w >> 1;
    const int lm = lane & 15, lq = lane >> 4;

    // staging coords: each thread owns (row, 16-wide k-half)
    const int srow = t >> 1, shalf = t & 1;
    const int sgm = m0 + srow;
    const bool svalid = (sgm < M);
    const float* srcrow = svalid ? ((sgm < split) ? xa + (size_t)sgm * KK
                                                  : xb + (size_t)(sgm - split) * KK)
                                 : xa;
    const int sbase = srow * SR + shalf * 16;

    f32x4 acc1[MI][NI] = {};
    f32x4 acc2[MI][NI] = {};

    for (int it = 0; it < NITER; ++it) {
        const int k0 = it * BK;
        // ---- stage A tile: hi/lo of A and of A*A ----
        {
            ushort hb[16], lb[16], shb[16], slb[16];
#pragma unroll
            for (int q = 0; q < 4; ++q) {
                float4 v = {0.f, 0.f, 0.f, 0.f};
                if (svalid) v = *(const float4*)(srcrow + k0 + shalf * 16 + q * 4);
                const float av[4] = {v.x, v.y, v.z, v.w};
#pragma unroll
                for (int j = 0; j < 4; ++j) {
                    int e = q * 4 + j;
                    split2(av[j], hb[e], lb[e]);
                    float sq = av[j] * av[j];
                    split2(sq, shb[e], slb[e]);
                }
            }
            *(u16x8*)(Ah + sbase)     = *(const u16x8*)&hb[0];
            *(u16x8*)(Ah + sbase + 8) = *(const u16x8*)&hb[8];
            *(u16x8*)(Al + sbase)     = *(const u16x8*)&lb[0];
            *(u16x8*)(Al + sbase + 8) = *(const u16x8*)&lb[8];
            *(u16x8*)(Sh + sbase)     = *(const u16x8*)&shb[0];
            *(u16x8*)(Sh + sbase + 8) = *(const u16x8*)&shb[8];
            *(u16x8*)(Sl + sbase)     = *(const u16x8*)&slb[0];
            *(u16x8*)(Sl + sbase + 8) = *(const u16x8*)&slb[8];
        }
        __syncthreads();

        // ---- B fragments straight from global (L1/L2-hit) ----
        bf16x8 b1h[NI], b1l[NI], b2h[NI], b2l[NI];
#pragma unroll
        for (int ni = 0; ni < NI; ++ni) {
            size_t wo = (size_t)(n0 + wn * WTN + ni * 16 + lm) * KK + k0 + lq * 8;
            b1h[ni] = *(const bf16x8*)(W1h + wo);
            b1l[ni] = *(const bf16x8*)(W1l + wo);
            b2h[ni] = *(const bf16x8*)(W2h + wo);
            b2l[ni] = *(const bf16x8*)(W2l + wo);
        }
#pragma unroll
        for (int mi = 0; mi < MI; ++mi) {
            int off = (wm * WTM + mi * 16 + lm) * SR + lq * 8;
            bf16x8 ah = *(const bf16x8*)(Ah + off);
            bf16x8 al = *(const bf16x8*)(Al + off);
            bf16x8 qh = *(const bf16x8*)(Sh + off);
            bf16x8 ql = *(const bf16x8*)(Sl + off);
#pragma unroll
            for (int ni = 0; ni < NI; ++ni) {
                acc1[mi][ni] = __builtin_amdgcn_mfma_f32_16x16x32_bf16(ah, b1h[ni], acc1[mi][ni], 0, 0, 0);
                acc1[mi][ni] = __builtin_amdgcn_mfma_f32_16x16x32_bf16(ah, b1l[ni], acc1[mi][ni], 0, 0, 0);
                acc1[mi][ni] = __builtin_amdgcn_mfma_f32_16x16x32_bf16(al, b1h[ni], acc1[mi][ni], 0, 0, 0);
                acc2[mi][ni] = __builtin_amdgcn_mfma_f32_16x16x32_bf16(qh, b2h[ni], acc2[mi][ni], 0, 0, 0);
                acc2[mi][ni] = __builtin_amdgcn_mfma_f32_16x16x32_bf16(qh, b2l[ni], acc2[mi][ni], 0, 0, 0);
                acc2[mi][ni] = __builtin_amdgcn_mfma_f32_16x16x32_bf16(ql, b2h[ni], acc2[mi][ni], 0, 0, 0);
            }
        }
        __syncthreads();
    }

    // ---- epilogue: C/D layout col=lane&15, row=lq*4+r; biases folded into C1 ----
#pragma unroll
    for (int mi = 0; mi < MI; ++mi)
#pragma unroll
        for (int ni = 0; ni < NI; ++ni)
#pragma unroll
            for (int r = 0; r < 4; ++r) {
                int gm = m0 + wm * WTM + mi * 16 + lq * 4 + r;
                int gn = n0 + wn * WTN + ni * 16 + lm;
                if (gm < M && gn < Nout) {
                    size_t o = (size_t)gm * Nout + gn;
                    float g1 = acc1[mi][ni][r];
                    C1[o] = g1 + bias1[gn] + bias2[gn];
                    C2[o] = g1 + acc2[mi][ni][r];
                }
            }
}

// ---------------------------------------------------------------------------
// T1 GEMM with fused gather (R4 simple loop, 4 blocks/CU):
//   e1 = relu( [final[u] ; final[it+U]] @ T1_W^T + T1_b ),  K = 896
// final = [embd(256) | f1(128) | f2(64)] per node; A-rows gathered on the fly
// (segment boundaries are 16-aligned so each staging thread's 16-float chunk
// lies in exactly one segment).
// ---------------------------------------------------------------------------

template <int TN, int KK>
__global__ __launch_bounds__(256, 4)
void gemm_t1_mfma(const int* __restrict__ userIdx, const int* __restrict__ itemIdx,
                  const float* __restrict__ uEmbd, const float* __restrict__ iEmbd,
                  const float* __restrict__ f1, const float* __restrict__ f2,
                  const ushort* __restrict__ Wh, const ushort* __restrict__ Wl,
                  const float* __restrict__ bias, float* __restrict__ C,
                  int M, int Nout) {
    constexpr int TM = 128, BK = 32, SR = BK + 8;
    constexpr int NITER = KK / BK;            // 28
    constexpr int WTM = 64, WTN = TN / 2;
    constexpr int MI = WTM / 16, NI = WTN / 16;
    __shared__ ushort Ah[TM * SR], Al[TM * SR];

    const int m0 = blockIdx.y * TM;
    const int n0 = blockIdx.x * TN;
    const int t  = threadIdx.x;
    const int lane = t & 63, w = t >> 6;
    const int wm = w & 1, wn = w >> 1;
    const int lm = lane & 15, lq = lane >> 4;

    const int srow = t >> 1, shalf = t & 1;
    const int b = m0 + srow;
    const bool svalid = (b < M);
    int unode = 0, gnode = 0;
    if (svalid) { unode = userIdx[b]; gnode = itemIdx[b] + USER_NUM; }
    const int sbase = srow * SR + shalf * 16;

    f32x4 acc[MI][NI] = {};

    for (int it = 0; it < NITER; ++it) {
        const int k0 = it * BK;
        {
            float4 v[4] = {};
            if (svalid) {
                int c0 = k0 + shalf * 16;
                int node = (c0 < 448) ? unode : gnode;
                int cc = (c0 < 448) ? c0 : c0 - 448;
                const float* p;
                if (cc < 256)
                    p = (node < USER_NUM) ? uEmbd + (size_t)node * 256 + cc
                                          : iEmbd + (size_t)(node - USER_NUM) * 256 + cc;
                else if (cc < 384) p = f1 + (size_t)node * 128 + (cc - 256);
                else               p = f2 + (size_t)node * 64  + (cc - 384);
#pragma unroll
                for (int q = 0; q < 4; ++q) v[q] = *(const float4*)(p + q * 4);
            }
            ushort hb[16], lb[16];
#pragma unroll
            for (int q = 0; q < 4; ++q) {
                const float av[4] = {v[q].x, v[q].y, v[q].z, v[q].w};
#pragma unroll
                for (int j = 0; j < 4; ++j) split2(av[j], hb[q * 4 + j], lb[q * 4 + j]);
            }
            *(u16x8*)(Ah + sbase)     = *(const u16x8*)&hb[0];
            *(u16x8*)(Ah + sbase + 8) = *(const u16x8*)&hb[8];
            *(u16x8*)(Al + sbase)     = *(const u16x8*)&lb[0];
            *(u16x8*)(Al + sbase + 8) = *(const u16x8*)&lb[8];
        }
        __syncthreads();

        bf16x8 bh[NI], bl[NI];
#pragma unroll
        for (int ni = 0; ni < NI; ++ni) {
            size_t wo = (size_t)(n0 + wn * WTN + ni * 16 + lm) * KK + k0 + lq * 8;
            bh[ni] = *(const bf16x8*)(Wh + wo);
            bl[ni] = *(const bf16x8*)(Wl + wo);
        }
#pragma unroll
        for (int mi = 0; mi < MI; ++mi) {
            int off = (wm * WTM + mi * 16 + lm) * SR + lq * 8;
            bf16x8 ah = *(const bf16x8*)(Ah + off);
            bf16x8 al = *(const bf16x8*)(Al + off);
#pragma unroll
            for (int ni = 0; ni < NI; ++ni) {
                acc[mi][ni] = __builtin_amdgcn_mfma_f32_16x16x32_bf16(ah, bh[ni], acc[mi][ni], 0, 0, 0);
                acc[mi][ni] = __builtin_amdgcn_mfma_f32_16x16x32_bf16(ah, bl[ni], acc[mi][ni], 0, 0, 0);
                acc[mi][ni] = __builtin_amdgcn_mfma_f32_16x16x32_bf16(al, bh[ni], acc[mi][ni], 0, 0, 0);
            }
        }
        __syncthreads();
    }

#pragma unroll
    for (int mi = 0; mi < MI; ++mi)
#pragma unroll
        for (int ni = 0; ni < NI; ++ni)
#pragma unroll
            for (int r = 0; r < 4; ++r) {
                int gm = m0 + wm * WTM + mi * 16 + lq * 4 + r;
                int gn = n0 + wn * WTN + ni * 16 + lm;
                if (gm < M && gn < Nout)
                    C[(size_t)gm * Nout + gn] = fmaxf(acc[mi][ni][r] + bias[gn], 0.f);
            }
}

// ---------------------------------------------------------------------------
// Fused SPMM epilogue (biases pre-folded into G1):
//   out[r,:] = sum_e val_e * H[col_e,:] + G1[r,:]
// 4 rows per 256-thread block, one wave per row, VEC floats per lane.
// ---------------------------------------------------------------------------

template <int VEC>
__global__ __launch_bounds__(256)
void spmm_fused(const int* __restrict__ row_ptr, const int* __restrict__ scol,
                const float* __restrict__ sval, const float* __restrict__ H,
                const float* __restrict__ G1, float* __restrict__ out, int n) {
    constexpr int W = 64 * VEC;
    int r = blockIdx.x * 4 + (threadIdx.x >> 6);
    if (r >= n) return;
    int base = (threadIdx.x & 63) * VEC;
    float acc[VEC];
    const float* g = G1 + (size_t)r * W + base;
#pragma unroll
    for (int v = 0; v < VEC; ++v) acc[v] = g[v];
    int e0 = row_ptr[r], e1 = row_ptr[r + 1];
    for (int e = e0; e < e1; ++e) {
        int c = scol[e];
        float val = sval[e];
        const float* h = H + (size_t)c * W + base;
#pragma unroll
        for (int v = 0; v < VEC; ++v) acc[v] += val * h[v];
    }
    float* o = out + (size_t)r * W + base;
#pragma unroll
    for (int v = 0; v < VEC; ++v) o[v] = acc[v];
}

// ---------------------------------------------------------------------------
// Fused T2+T3 tail: out[b] = T3_W . relu(T2_W @ e1[b] + T2_b) + T3_b
// One wave per batch row; lanes 0..31 each own one of the 32 T2 outputs.
// ---------------------------------------------------------------------------

__global__ __launch_bounds__(256)
void mlp_tail(const float* __restrict__ e1, const float* __restrict__ T2_W,
              const float* __restrict__ T2_b, const float* __restrict__ T3_W,
              const float* __restrict__ T3_b, float* __restrict__ out, int B) {
    int wid = (blockIdx.x * 256 + threadIdx.x) >> 6;
    if (wid >= B) return;
    int lane = threadIdx.x & 63;
    float s = 0.f;
    if (lane < 32) {
        const float* er = e1 + (size_t)wid * 64;
        const float* wr = T2_W + lane * 64;
        float d = T2_b[lane];
#pragma unroll
        for (int k = 0; k < 64; ++k) d += er[k] * wr[k];
        s = fmaxf(d, 0.f) * T3_W[lane];
    }
#pragma unroll
    for (int off2 = 16; off2 > 0; off2 >>= 1) s += __shfl_down(s, off2);
    if (lane == 0) out[wid] = s + T3_b[0];
}

// ---------------------------------------------------------------------------

extern "C" void kernel_launch(void* const* d_in, const int* in_sizes, int n_in,
                              void* d_out, int out_size, void* d_ws, size_t ws_size,
                              hipStream_t stream) {
    const int* userIdx  = (const int*)d_in[0];
    const int* itemIdx  = (const int*)d_in[1];
    const int* edge_row = (const int*)d_in[2];
    const int* edge_col = (const int*)d_in[3];
    const float* edge_val = (const float*)d_in[4];
    const float* uEmbd  = (const float*)d_in[5];
    const float* iEmbd  = (const float*)d_in[6];
    const float* W1_0 = (const float*)d_in[7];
    const float* b1_0 = (const float*)d_in[8];
    const float* W2_0 = (const float*)d_in[9];
    const float* b2_0 = (const float*)d_in[10];
    const float* W1_1 = (const float*)d_in[11];
    const float* b1_1 = (const float*)d_in[12];
    const float* W2_1 = (const float*)d_in[13];
    const float* b2_1 = (const float*)d_in[14];
    const float* T1_W = (const float*)d_in[15];
    const float* T1_b = (const float*)d_in[16];
    const float* T2_W = (const float*)d_in[17];
    const float* T2_b = (const float*)d_in[18];
    const float* T3_W = (const float*)d_in[19];
    const float* T3_b = (const float*)d_in[20];
    float* out = (float*)d_out;

    const int B   = in_sizes[0];
    const int NNZ = in_sizes[2];
    const int N   = NTOT;

    // ---- workspace carve-up (bytes, 256-aligned) ----
    uint8_t* ws = (uint8_t*)d_ws;
    size_t off = 0;
    auto alloc = [&](size_t bytes) {
        void* p = ws + off;
        off += (bytes + 255) & ~(size_t)255;
        return p;
    };
    float* bufA = (float*)alloc((size_t)N * 128 * 4);  // G1_0; later G1_1 | H_1
    float* bufB = (float*)alloc((size_t)N * 128 * 4);  // H_0;  later f2
    float* f1   = (float*)alloc((size_t)N * 128 * 4);
    float* e1   = (float*)alloc((size_t)B * 64 * 4);
    int*   counts  = (int*)alloc((size_t)2 * N * 4);   // counts[N] + fill[N]
    int*   fill    = counts + N;
    int*   row_ptr = (int*)alloc((size_t)(N + 1) * 4);
    int*   blk_sums= (int*)alloc(128 * 4);
    int*   scol    = (int*)alloc((size_t)NNZ * 4);
    float* sval    = (float*)alloc((size_t)NNZ * 4);
    // pre-split weight matrices (hi/lo bf16 stored as ushort)
    ushort* W10h = (ushort*)alloc(128 * 256 * 2);
    ushort* W10l = (ushort*)alloc(128 * 256 * 2);
    ushort* W20h = (ushort*)alloc(128 * 256 * 2);
    ushort* W20l = (ushort*)alloc(128 * 256 * 2);
    ushort* W11h = (ushort*)alloc(64 * 128 * 2);
    ushort* W11l = (ushort*)alloc(64 * 128 * 2);
    ushort* W21h = (ushort*)alloc(64 * 128 * 2);
    ushort* W21l = (ushort*)alloc(64 * 128 * 2);
    ushort* T1h  = (ushort*)alloc(64 * 896 * 2);
    ushort* T1l  = (ushort*)alloc(64 * 896 * 2);
    (void)ws_size; (void)n_in; (void)out_size;

    float* G1_0 = bufA;
    float* H_0  = bufB;
    float* G1_1 = bufA;
    float* H_1  = bufA + (size_t)N * 64;
    float* f2   = bufB;

    // ---- build CSR ----
    hipMemsetAsync(counts, 0, (size_t)2 * N * 4, stream);
    hist_rows<<<(NNZ + 255) / 256, 256, 0, stream>>>(edge_row, counts, NNZ);
    int nb = (N + 1023) / 1024;   // 98
    scan_block<<<nb, 1024, 0, stream>>>(counts, row_ptr, blk_sums, N);
    scan_sums<<<1, 128, 0, stream>>>(blk_sums, nb);
    scan_add<<<nb, 1024, 0, stream>>>(row_ptr, blk_sums, N, NNZ);
    scatter_edges<<<(NNZ + 255) / 256, 256, 0, stream>>>(edge_row, edge_col, edge_val,
                                                         row_ptr, fill, scol, sval, NNZ);

    // ---- pre-split weights ----
    split_w<<<(32768 + 255) / 256, 256, 0, stream>>>(W1_0, W10h, W10l, 32768);
    split_w<<<(32768 + 255) / 256, 256, 0, stream>>>(W2_0, W20h, W20l, 32768);
    split_w<<<(8192 + 255) / 256, 256, 0, stream>>>(W1_1, W11h, W11l, 8192);
    split_w<<<(8192 + 255) / 256, 256, 0, stream>>>(W2_1, W21h, W21l, 8192);
    split_w<<<(57344 + 255) / 256, 256, 0, stream>>>(T1_W, T1h, T1l, 57344);

    // ---- layer 0: G1_0 = F@W1_0^T (+biases), H_0 = F@W1_0^T + (F*F)@W2_0^T ----
    {
        dim3 grid(2, (N + 127) / 128);   // TN=64, Nout=128
        gemm_dual_mfma<64, 256><<<grid, 256, 0, stream>>>(
            uEmbd, iEmbd, USER_NUM, W10h, W10l, W20h, W20l, b1_0, b2_0, G1_0, H_0, N, 128);
    }
    // f1 = spmm(H_0) + G1_0   (biases already in G1_0)
    spmm_fused<2><<<(N + 3) / 4, 256, 0, stream>>>(row_ptr, scol, sval, H_0, G1_0, f1, N);

    // ---- layer 1: G1_1 = f1@W1_1^T (+biases), H_1 = f1@W1_1^T + (f1*f1)@W2_1^T ----
    {
        dim3 grid(1, (N + 127) / 128);   // TN=64, Nout=64
        gemm_dual_mfma<64, 128><<<grid, 256, 0, stream>>>(
            f1, f1, N, W11h, W11l, W21h, W21l, b1_1, b2_1, G1_1, H_1, N, 64);
    }
    // f2 = spmm(H_1) + G1_1
    spmm_fused<1><<<(N + 3) / 4, 256, 0, stream>>>(row_ptr, scol, sval, H_1, G1_1, f2, N);

    // ---- fused gather + T1 GEMM, then fused T2+T3 tail ----
    {
        dim3 grid(1, (B + 127) / 128);   // TN=64, K=896
        gemm_t1_mfma<64, 896><<<grid, 256, 0, stream>>>(
            userIdx, itemIdx, uEmbd, iEmbd, f1, f2, T1h, T1l, T1_b, e1, B, 64);
    }
    mlp_tail<<<(B * 64 + 255) / 256, 256, 0, stream>>>(e1, T2_W, T2_b, T3_W, T3_b, out, B);
}